// Round 6
// baseline (31.708 us; speedup 1.0000x reference)
//
#include <hip/hip_runtime.h>

#define PAD 2
#define PX 4                 // pixels per thread along x
#define PY 2                 // pixels per thread along y
#define BDX 16
#define BDY 16
#define TSX (BDX * PX)       // 64 outputs wide per block
#define TSY (BDY * PY)       // 32 outputs high per block
#define LTW (TSX + 2 * PAD)  // 68 floats (= 17 float4 chunks per row)
#define LTH (TSY + 2 * PAD)  // 36 rows
#define NCHUNK (LTH * LTW / 4)  // 612

// 16B vector with only 4B alignment guarantee (global loads at -2 offset)
typedef float float4u __attribute__((vector_size(16), aligned(4)));
typedef float v4f __attribute__((ext_vector_type(4)));

__device__ __forceinline__ float min3f(float a, float b, float c) {
    return fminf(fminf(a, b), c);   // clang fuses to v_min3_f32
}
__device__ __forceinline__ float max3f(float a, float b, float c) {
    return fmaxf(fmaxf(a, b), c);   // clang fuses to v_max3_f32
}
__device__ __forceinline__ float med3f(float a, float b, float c) {
    // median3 = max(min(a,b), min(max(a,b),c)) -> v_med3_f32 pattern
    return fmaxf(fminf(a, b), fminf(fmaxf(a, b), c));
}

// compare-exchange (dead halves are DCE'd)
#define CE(a, b) { float _lo = fminf(a, b), _hi = fmaxf(a, b); (a) = _lo; (b) = _hi; }

// insert e into sorted (s1<=s2<=s3<=s4) -> o0..o4 sorted ascending (8 ops)
#define INSERT5(o0, o1, o2, o3, o4, s1, s2, s3, s4, e) { \
    float _t  = fminf(s4, e);   o4 = fmaxf(s4, e); \
    float _t2 = fminf(s3, _t);  o3 = fmaxf(s3, _t); \
    float _t3 = fminf(s2, _t2); o2 = fmaxf(s2, _t2); \
    o0 = fminf(s1, _t3);        o1 = fmaxf(s1, _t3); }

// full sort of 4 (5-CE optimal network)
#define SORT4(t0, t1, t2, t3) \
    CE(t0, t1) CE(t2, t3) CE(t0, t2) CE(t1, t3) CE(t1, t2)

// median of 9 in q4 (Devillard 19-CE network)
#define MED9(q0, q1, q2, q3, q4, q5, q6, q7, q8) \
    CE(q1, q2) CE(q4, q5) CE(q7, q8) \
    CE(q0, q1) CE(q3, q4) CE(q6, q7) \
    CE(q1, q2) CE(q4, q5) CE(q7, q8) \
    CE(q0, q3) CE(q5, q8) CE(q4, q7) \
    CE(q3, q6) CE(q1, q4) CE(q2, q5) \
    CE(q4, q7) CE(q4, q2) CE(q6, q4) \
    CE(q4, q2)

__global__ __launch_bounds__(256) void denoise_median5_kernel(
    const float* __restrict__ x,
    const float* __restrict__ noise_var_p,
    const float* __restrict__ noise_bias_p,
    float* __restrict__ out,
    int H, int W)
{
    __shared__ float tile[LTH][LTW];

    const float noise_var  = noise_var_p[0];
    const float noise_bias = noise_bias_p[0];

    const int b      = blockIdx.z;
    const int tile_y = blockIdx.y * TSY;
    const int tile_x = blockIdx.x * TSX;
    const int tx = threadIdx.x;
    const int ty = threadIdx.y;
    const int tid = ty * BDX + tx;

    const float* __restrict__ img = x + (size_t)b * H * W;

    const bool interior = (blockIdx.x > 0) && (blockIdx.x < gridDim.x - 1) &&
                          (blockIdx.y > 0) && (blockIdx.y < gridDim.y - 1);
    if (interior) {
        // Vectorized staging: 612 float4 chunks, chunk i -> tile[i/17][(i%17)*4].
        const float* gbase = img + (size_t)(tile_y - PAD) * W + (tile_x - PAD);
        {
            const int i = tid;
            const int row = i / 17, cc = i - row * 17;
            *(float4u*)&tile[row][cc * 4] = *(const float4u*)(gbase + (size_t)row * W + cc * 4);
        }
        {
            const int i = tid + 256;
            const int row = i / 17, cc = i - row * 17;
            *(float4u*)&tile[row][cc * 4] = *(const float4u*)(gbase + (size_t)row * W + cc * 4);
        }
        if (tid < NCHUNK - 512) {          // 100 remaining chunks
            const int i = tid + 512;
            const int row = i / 17, cc = i - row * 17;
            *(float4u*)&tile[row][cc * 4] = *(const float4u*)(gbase + (size_t)row * W + cc * 4);
        }
    } else {
        // Edge blocks: scalar bounds-checked staging (zero pad).
        for (int i = tid; i < LTH * LTW; i += BDX * BDY) {
            const int ly = i / LTW;
            const int lx = i - ly * LTW;
            const int gy = tile_y + ly - PAD;
            const int gx = tile_x + lx - PAD;
            float v = 0.0f;
            if (gy >= 0 && gy < H && gx >= 0 && gx < W)
                v = img[(size_t)gy * W + gx];
            tile[ly][lx] = v;
        }
    }
    __syncthreads();

    // 6 input rows (ty*2 .. ty*2+5), two float4 fragments per row.
    v4f A[6], Dq[6];
    #pragma unroll
    for (int r = 0; r < 6; ++r) {
        A[r]  = *(const v4f*)&tile[ty * PY + r][tx * PX];
        Dq[r] = *(const v4f*)&tile[ty * PY + r][tx * PX + 4];
    }

    // Packed column sums / sums-of-squares; rows 1..4 shared between windows.
    v4f SAsh = (A[1] + A[2]) + (A[3] + A[4]);
    v4f SDsh = (Dq[1] + Dq[2]) + (Dq[3] + Dq[4]);
    v4f QAsh = A[1] * A[1];  QAsh = A[2] * A[2] + QAsh;
    QAsh = A[3] * A[3] + QAsh;  QAsh = A[4] * A[4] + QAsh;
    v4f QDsh = Dq[1] * Dq[1];  QDsh = Dq[2] * Dq[2] + QDsh;
    QDsh = Dq[3] * Dq[3] + QDsh;  QDsh = Dq[4] * Dq[4] + QDsh;

    const v4f SA_A = SAsh + A[0],  SD_A = SDsh + Dq[0];
    const v4f SA_B = SAsh + A[5],  SD_B = SDsh + Dq[5];
    const v4f QA_A = A[0] * A[0] + QAsh,   QD_A = Dq[0] * Dq[0] + QDsh;
    const v4f QA_B = A[5] * A[5] + QAsh,   QD_B = Dq[5] * Dq[5] + QDsh;

    float sum5A[PX], sq5A[PX], sum5B[PX], sq5B[PX];
    {
        const float sA8[8] = {SA_A.x, SA_A.y, SA_A.z, SA_A.w, SD_A.x, SD_A.y, SD_A.z, SD_A.w};
        const float qA8[8] = {QA_A.x, QA_A.y, QA_A.z, QA_A.w, QD_A.x, QD_A.y, QD_A.z, QD_A.w};
        const float sB8[8] = {SA_B.x, SA_B.y, SA_B.z, SA_B.w, SD_B.x, SD_B.y, SD_B.z, SD_B.w};
        const float qB8[8] = {QA_B.x, QA_B.y, QA_B.z, QA_B.w, QD_B.x, QD_B.y, QD_B.z, QD_B.w};
        sum5A[0] = ((sA8[0] + sA8[1]) + (sA8[2] + sA8[3])) + sA8[4];
        sq5A[0]  = ((qA8[0] + qA8[1]) + (qA8[2] + qA8[3])) + qA8[4];
        sum5B[0] = ((sB8[0] + sB8[1]) + (sB8[2] + sB8[3])) + sB8[4];
        sq5B[0]  = ((qB8[0] + qB8[1]) + (qB8[2] + qB8[3])) + qB8[4];
        #pragma unroll
        for (int p = 1; p < PX; ++p) {
            sum5A[p] = sum5A[p - 1] - sA8[p - 1] + sA8[p + 4];
            sq5A[p]  = sq5A[p - 1]  - qA8[p - 1] + qA8[p + 4];
            sum5B[p] = sum5B[p - 1] - sB8[p - 1] + sB8[p + 4];
            sq5B[p]  = sq5B[p - 1]  - qB8[p - 1] + qB8[p + 4];
        }
    }

    // Center pixels (raw): window A center row = input row 2; B = row 3.
    const float centerA[PX] = {A[2].z, A[2].w, Dq[2].x, Dq[2].y};
    const float centerB[PX] = {A[3].z, A[3].w, Dq[3].x, Dq[3].y};

    // Unpack to 8 columns x 6 rows; sort shared rows 1..4 per column.
    float c[8][6];
    #pragma unroll
    for (int r = 0; r < 6; ++r) {
        c[0][r] = A[r].x;  c[1][r] = A[r].y;  c[2][r] = A[r].z;  c[3][r] = A[r].w;
        c[4][r] = Dq[r].x; c[5][r] = Dq[r].y; c[6][r] = Dq[r].z; c[7][r] = Dq[r].w;
    }
    #pragma unroll
    for (int k = 0; k < 8; ++k) {
        SORT4(c[k][1], c[k][2], c[k][3], c[k][4]);
    }

    float* outp = out + (size_t)b * H * W;
    const int oy0 = tile_y + ty * PY;
    const int ox  = tile_x + tx * PX;

    // One window: col[8][5] sorted columns -> 4 outputs.
    auto run_window = [&](const float (&col)[8][5], const float (&center)[PX],
                          const float (&sum5)[PX], const float (&sq5)[PX]) -> float4 {
        float4 res;
        float* resp = (float*)&res;
        #pragma unroll
        for (int p = 0; p < PX; ++p) {
            float A1, A2, B1, B2, B3, C1, C2, C3, D1, D2, D3, E1, E2;
            // row 0 (column minima): sorted pos 3,4
            {
                const float a1 = fminf(col[p][0], col[p+1][0]), a2 = fmaxf(col[p][0], col[p+1][0]);
                const float b1 = fminf(col[p+2][0], col[p+3][0]), b2 = fmaxf(col[p+2][0], col[p+3][0]);
                const float cc = col[p+4][0];
                const float M = fmaxf(a2, b2), t1 = fminf(a2, b2), t3 = fmaxf(a1, b1);
                A2 = fmaxf(M, cc);
                A1 = max3f(t1, fminf(cc, M), t3);
            }
            // row 1: sorted pos 2,3,4
            {
                const float a1 = fminf(col[p][1], col[p+1][1]), a2 = fmaxf(col[p][1], col[p+1][1]);
                const float b1 = fminf(col[p+2][1], col[p+3][1]), b2 = fmaxf(col[p+2][1], col[p+3][1]);
                const float cc = col[p+4][1];
                const float M = fmaxf(a2, b2), t1 = fminf(a2, b2), t3 = fmaxf(a1, b1);
                B3 = fmaxf(M, cc);
                B2 = max3f(t1, fminf(cc, M), t3);
                B1 = med3f(t1, t3, cc);
            }
            // row 2: sorted pos 1,2,3
            {
                const float a1 = fminf(col[p][2], col[p+1][2]), a2 = fmaxf(col[p][2], col[p+1][2]);
                const float b1 = fminf(col[p+2][2], col[p+3][2]), b2 = fmaxf(col[p+2][2], col[p+3][2]);
                const float cc = col[p+4][2];
                const float M = fmaxf(a2, b2), m = fminf(a1, b1);
                const float t1 = fminf(a2, b2), t3 = fmaxf(a1, b1);
                C2 = med3f(t1, t3, cc);
                C3 = max3f(t1, fminf(cc, M), t3);
                C1 = min3f(t3, fmaxf(cc, m), t1);
            }
            // row 3: sorted pos 0,1,2
            {
                const float a1 = fminf(col[p][3], col[p+1][3]), a2 = fmaxf(col[p][3], col[p+1][3]);
                const float b1 = fminf(col[p+2][3], col[p+3][3]), b2 = fmaxf(col[p+2][3], col[p+3][3]);
                const float cc = col[p+4][3];
                const float m = fminf(a1, b1), t1 = fminf(a2, b2), t3 = fmaxf(a1, b1);
                D1 = fminf(m, cc);
                D2 = min3f(t3, fmaxf(cc, m), t1);
                D3 = med3f(t1, t3, cc);
            }
            // row 4 (column maxima): sorted pos 0,1
            {
                const float a1 = fminf(col[p][4], col[p+1][4]), a2 = fmaxf(col[p][4], col[p+1][4]);
                const float b1 = fminf(col[p+2][4], col[p+3][4]), b2 = fmaxf(col[p+2][4], col[p+3][4]);
                const float cc = col[p+4][4];
                const float m = fminf(a1, b1), t1 = fminf(a2, b2), t3 = fmaxf(a1, b1);
                E1 = fminf(m, cc);
                E2 = min3f(t3, fmaxf(cc, m), t1);
            }

            // poset elimination: 13 candidates -> 9 (rank-counted, provably safe)
            const float mn1 = fminf(B3, D3);
            const float mn2 = fminf(C3, E2);
            const float mx1 = fmaxf(B1, D1);
            const float mx2 = fmaxf(A1, C1);

            float q0 = mx2, q1 = A2, q2 = B2, q3 = C2, q4 = D2,
                  q5 = E1, q6 = mx1, q7 = mn1, q8 = mn2;
            MED9(q0, q1, q2, q3, q4, q5, q6, q7, q8);
            const float mid = q4;

            const float sum = sum5[p];
            const float sq  = sq5[p];
            const float mean = sum * (1.0f / 25.0f);
            float var = (sq - sum * mean) * (1.0f / 24.0f);
            var = fmaxf(var, 0.0f);

            const float xc = center[p];
            const float rr = __builtin_amdgcn_rcpf(var + 1e-10f);
            float y = xc - noise_var * rr * (xc - mid + noise_bias);
            resp[p] = fmaxf(y, 0.0f);
        }
        return res;
    };

    // ---- window A (input rows 0..4): insert row0 into shared sorted rows 1..4 ----
    {
        float colA[8][5];
        #pragma unroll
        for (int k = 0; k < 8; ++k) {
            INSERT5(colA[k][0], colA[k][1], colA[k][2], colA[k][3], colA[k][4],
                    c[k][1], c[k][2], c[k][3], c[k][4], c[k][0]);
        }
        float4 resA = run_window(colA, centerA, sum5A, sq5A);
        *(float4*)&outp[(size_t)oy0 * W + ox] = resA;
    }

    // ---- window B (input rows 1..5): insert row5 ----
    {
        float colB[8][5];
        #pragma unroll
        for (int k = 0; k < 8; ++k) {
            INSERT5(colB[k][0], colB[k][1], colB[k][2], colB[k][3], colB[k][4],
                    c[k][1], c[k][2], c[k][3], c[k][4], c[k][5]);
        }
        float4 resB = run_window(colB, centerB, sum5B, sq5B);
        *(float4*)&outp[(size_t)(oy0 + 1) * W + ox] = resB;
    }
}

extern "C" void kernel_launch(void* const* d_in, const int* in_sizes, int n_in,
                              void* d_out, int out_size, void* d_ws, size_t ws_size,
                              hipStream_t stream)
{
    const float* x  = (const float*)d_in[0];
    const float* nv = (const float*)d_in[1];
    const float* nb = (const float*)d_in[2];
    float* out = (float*)d_out;

    const int H = 512, W = 512;
    const int B = in_sizes[0] / (H * W);   // 16 (C==1)

    dim3 block(BDX, BDY, 1);
    dim3 grid(W / TSX, H / TSY, B);
    denoise_median5_kernel<<<grid, block, 0, stream>>>(x, nv, nb, out, H, W);
}